// Round 8
// baseline (81.209 us; speedup 1.0000x reference)
//
#include <hip/hip_runtime.h>
#include <math.h>

// Problem constants (match reference setup_inputs)
#define NC    64     // nodes per graph
#define NT    128    // time samples
#define NS    8      // seq len
#define NFEAT 16     // features per GCN step
#define NE1   4032   // edges per graph
#define NB    1024   // graphs

__device__ __forceinline__ float sigmoidf_(float x) { return 1.f / (1.f + expf(-x)); }

// ---------------------------------------------------------------------------
// Kernel A: per step s, build normalized adjacency M_s (64x64) from graph-0
// edges, then P2 = M^2, P3 = M^3. Store all three in j-major interleaved
// layout: Pws[s][k][jj][n][f] = Matk[n][4*jj+f]  (k=0:M, 1:P2, 2:P3), so
// kernel B's lane-n float4 load of 4 consecutive m's is fully coalesced.
// ---------------------------------------------------------------------------
__global__ __launch_bounds__(256) void build_powers_kernel(
    const int* __restrict__ ei, long long E_total,
    const float* __restrict__ ew, float* __restrict__ Pws) {
  const int s = blockIdx.x;
  const int t = threadIdx.x;
  __shared__ float M[64][64];
  __shared__ float P2[64][64];
  __shared__ float P3[64][64];
  __shared__ float deg[64];

  for (int i = t; i < 4096; i += 256) (&M[0][0])[i] = 0.f;
  if (t < 64) deg[t] = 0.f;
  __syncthreads();

  const int* row = ei;              // edge_index[0][e]
  const int* col = ei + E_total;    // edge_index[1][e]
  const float* w = ew + s * NE1;

  for (int e = t; e < NE1; e += 256) atomicAdd(&deg[col[e]], w[e]);
  __syncthreads();
  if (t < 64) { float d = deg[t]; deg[t] = (d > 0.f) ? rsqrtf(d) : 0.f; }
  __syncthreads();
  for (int e = t; e < NE1; e += 256) {
    int r = row[e], c = col[e];
    atomicAdd(&M[c][r], deg[r] * w[e] * deg[c]);   // h_new[c] = sum_r M[c][r] h[r]
  }
  __syncthreads();

  const int j  = t & 63;
  const int ib = (t >> 6) * 16;
  for (int ii = 0; ii < 16; ++ii) {
    int i = ib + ii;
    float acc = 0.f;
#pragma unroll
    for (int m = 0; m < 64; ++m) acc = fmaf(M[i][m], M[m][j], acc);
    P2[i][j] = acc;
  }
  __syncthreads();
  for (int ii = 0; ii < 16; ++ii) {
    int i = ib + ii;
    float acc = 0.f;
#pragma unroll
    for (int m = 0; m < 64; ++m) acc = fmaf(M[i][m], P2[m][j], acc);
    P3[i][j] = acc;
  }
  __syncthreads();

  float* dst = Pws + (size_t)s * 12288;
  for (int i = t; i < 12288; i += 256) {
    int k   = i >> 12;
    int rem = i & 4095;
    int jj  = rem >> 8;
    int r2  = rem & 255;
    int n   = r2 >> 2;
    int f   = r2 & 3;
    float v = (k == 0) ? M[n][(jj << 2) | f]
            : (k == 1) ? P2[n][(jj << 2) | f]
                       : P3[n][(jj << 2) | f];
    dst[i] = v;
  }
}

// ---------------------------------------------------------------------------
// Kernel B: fused TAGConv(K=3, powers form) + ReLU + per-graph max-pool.
// out = V0 + P1*V1 + P2*V2 + P3*V3 ; all P-loads and z-broadcasts are
// independent after stage 1 (no sequential Horner stages). P rows stream
// from global/L2 (coalesced j-major float4, shared by the wave's 2 graphs);
// z (=V1..V3) broadcasts via per-wave private LDS read with uniform-address
// ds_read_b128 (HW broadcast, no conflicts). 2 graphs per wave.
// NOTE: no min-waves arg in __launch_bounds__ (a (256,4) bound spilled
// M-in-regs to scratch in round 3).
// ---------------------------------------------------------------------------
__global__ __launch_bounds__(256) void tag_pool_kernel(
    const float* __restrict__ x, const float* __restrict__ Pws,
    const float* __restrict__ lin_w, const float* __restrict__ lin_b,
    float* __restrict__ pooled) {
  const int t    = threadIdx.x;
  const int lane = t & 63;
  const int w    = t >> 6;
  const int wid  = (blockIdx.x << 2) | w;       // 4096 waves
  const int s    = wid >> 9;                    // 512 waves per step
  const int g0   = (wid & 511) << 1;            // 2 graphs per wave

  __shared__ __align__(16) float Wl[16][16];        // [k*4+o][f]
  __shared__ __align__(16) float Zb[4][2][3][64][4];// per-wave z bufs (V1..V3)
  __shared__ float bsum4[4];

  // issue global x loads early (both graphs)
  float xf0[16], xf1[16];
  {
    const float* xr0 = x + (((size_t)(g0 + 0) << 6) + lane) * NT + s * NFEAT;
    const float* xr1 = x + (((size_t)(g0 + 1) << 6) + lane) * NT + s * NFEAT;
    *(float4*)(&xf0[0])  = *(const float4*)(xr0);
    *(float4*)(&xf0[4])  = *(const float4*)(xr0 + 4);
    *(float4*)(&xf0[8])  = *(const float4*)(xr0 + 8);
    *(float4*)(&xf0[12]) = *(const float4*)(xr0 + 12);
    *(float4*)(&xf1[0])  = *(const float4*)(xr1);
    *(float4*)(&xf1[4])  = *(const float4*)(xr1 + 4);
    *(float4*)(&xf1[8])  = *(const float4*)(xr1 + 8);
    *(float4*)(&xf1[12]) = *(const float4*)(xr1 + 12);
  }

  Wl[t >> 4][t & 15] = lin_w[t];               // 256 floats
  if (t < 4) bsum4[t] = lin_b[t] + lin_b[4 + t] + lin_b[8 + t] + lin_b[12 + t];
  __syncthreads();

  // stage 1: V[k][o] = sum_f x[f] * W[k][o][f] for both graphs.
  // k=0 -> accumulators A; k=1..3 -> this wave's private LDS z-buffers.
  float A0[4], A1[4];
#pragma unroll
  for (int k = 0; k < 4; ++k) {
    float v0[4], v1[4];
#pragma unroll
    for (int o = 0; o < 4; ++o) {
      const int ko = (k << 2) | o;
      const float4 w0 = *(const float4*)(&Wl[ko][0]);
      const float4 w1 = *(const float4*)(&Wl[ko][4]);
      const float4 w2 = *(const float4*)(&Wl[ko][8]);
      const float4 w3 = *(const float4*)(&Wl[ko][12]);
      float a0 = 0.f, a1 = 0.f;
      a0 = fmaf(xf0[0],  w0.x, a0); a1 = fmaf(xf1[0],  w0.x, a1);
      a0 = fmaf(xf0[1],  w0.y, a0); a1 = fmaf(xf1[1],  w0.y, a1);
      a0 = fmaf(xf0[2],  w0.z, a0); a1 = fmaf(xf1[2],  w0.z, a1);
      a0 = fmaf(xf0[3],  w0.w, a0); a1 = fmaf(xf1[3],  w0.w, a1);
      a0 = fmaf(xf0[4],  w1.x, a0); a1 = fmaf(xf1[4],  w1.x, a1);
      a0 = fmaf(xf0[5],  w1.y, a0); a1 = fmaf(xf1[5],  w1.y, a1);
      a0 = fmaf(xf0[6],  w1.z, a0); a1 = fmaf(xf1[6],  w1.z, a1);
      a0 = fmaf(xf0[7],  w1.w, a0); a1 = fmaf(xf1[7],  w1.w, a1);
      a0 = fmaf(xf0[8],  w2.x, a0); a1 = fmaf(xf1[8],  w2.x, a1);
      a0 = fmaf(xf0[9],  w2.y, a0); a1 = fmaf(xf1[9],  w2.y, a1);
      a0 = fmaf(xf0[10], w2.z, a0); a1 = fmaf(xf1[10], w2.z, a1);
      a0 = fmaf(xf0[11], w2.w, a0); a1 = fmaf(xf1[11], w2.w, a1);
      a0 = fmaf(xf0[12], w3.x, a0); a1 = fmaf(xf1[12], w3.x, a1);
      a0 = fmaf(xf0[13], w3.y, a0); a1 = fmaf(xf1[13], w3.y, a1);
      a0 = fmaf(xf0[14], w3.z, a0); a1 = fmaf(xf1[14], w3.z, a1);
      a0 = fmaf(xf0[15], w3.w, a0); a1 = fmaf(xf1[15], w3.w, a1);
      v0[o] = a0; v1[o] = a1;
    }
    if (k == 0) {
#pragma unroll
      for (int o = 0; o < 4; ++o) { A0[o] = v0[o]; A1[o] = v1[o]; }
    } else {
      *(float4*)(&Zb[w][0][k - 1][lane][0]) = make_float4(v0[0], v0[1], v0[2], v0[3]);
      *(float4*)(&Zb[w][1][k - 1][lane][0]) = make_float4(v1[0], v1[1], v1[2], v1[3]);
    }
  }
  // wave-local LDS ordering: no barrier needed before reading own Zb

  // main loop: A += sum_k sum_m Pk[lane][m] * zk[m]   (all reads independent)
  const float* Pb  = Pws + (size_t)s * 12288 + (lane << 2);
  const float* zb0 = &Zb[w][0][0][0][0];
  const float* zb1 = &Zb[w][1][0][0][0];
#pragma unroll 1
  for (int k = 0; k < 3; ++k) {
    const float* Pk = Pb + (k << 12);
    const float* z0k = zb0 + (k << 8);
    const float* z1k = zb1 + (k << 8);
#pragma unroll
    for (int jj = 0; jj < 16; ++jj) {
      const float4 p4 = *(const float4*)(Pk + (jj << 8));   // coalesced, L2-hit
      const float pv[4] = {p4.x, p4.y, p4.z, p4.w};
#pragma unroll
      for (int f = 0; f < 4; ++f) {
        const int m = (jj << 2) | f;
        const float4 z0 = *(const float4*)(z0k + (m << 2)); // uniform b128 bcast
        const float4 z1 = *(const float4*)(z1k + (m << 2));
        const float p = pv[f];
        A0[0] = fmaf(p, z0.x, A0[0]);
        A0[1] = fmaf(p, z0.y, A0[1]);
        A0[2] = fmaf(p, z0.z, A0[2]);
        A0[3] = fmaf(p, z0.w, A0[3]);
        A1[0] = fmaf(p, z1.x, A1[0]);
        A1[1] = fmaf(p, z1.y, A1[1]);
        A1[2] = fmaf(p, z1.z, A1[2]);
        A1[3] = fmaf(p, z1.w, A1[3]);
      }
    }
  }

  // epilogue: bias, relu, max over 64 nodes, store (per graph)
  const float b0 = bsum4[0], b1 = bsum4[1], b2 = bsum4[2], b3 = bsum4[3];
#pragma unroll
  for (int gi = 0; gi < 2; ++gi) {
    float o0 = fmaxf((gi ? A1[0] : A0[0]) + b0, 0.f);
    float o1 = fmaxf((gi ? A1[1] : A0[1]) + b1, 0.f);
    float o2 = fmaxf((gi ? A1[2] : A0[2]) + b2, 0.f);
    float o3 = fmaxf((gi ? A1[3] : A0[3]) + b3, 0.f);
#pragma unroll
    for (int off = 32; off > 0; off >>= 1) {
      o0 = fmaxf(o0, __shfl_xor(o0, off));
      o1 = fmaxf(o1, __shfl_xor(o1, off));
      o2 = fmaxf(o2, __shfl_xor(o2, off));
      o3 = fmaxf(o3, __shfl_xor(o3, off));
    }
    if (lane == 0)
      *(float4*)(pooled + ((size_t)(g0 + gi) * NS + s) * 4) = make_float4(o0, o1, o2, o3);
  }
}

// ---------------------------------------------------------------------------
// Kernel C: LSTM (hidden 4, 8 steps) + FC. One thread per graph.
// ---------------------------------------------------------------------------
__global__ __launch_bounds__(64) void lstm_fc_kernel(
    const float* __restrict__ pooled,
    const float* __restrict__ w_ih, const float* __restrict__ b_ih,
    const float* __restrict__ w_hh, const float* __restrict__ b_hh,
    const float* __restrict__ fc_w, const float* __restrict__ fc_b,
    float* __restrict__ out) {
  const int g = blockIdx.x * blockDim.x + threadIdx.x;
  if (g >= NB) return;
  float h[4] = {0.f, 0.f, 0.f, 0.f};
  float c[4] = {0.f, 0.f, 0.f, 0.f};
  for (int s = 0; s < NS; ++s) {
    float4 xt4 = *(const float4*)(pooled + (((size_t)g << 3) + s) * 4);
    const float xv[4] = {xt4.x, xt4.y, xt4.z, xt4.w};
    float gates[16];
#pragma unroll
    for (int j = 0; j < 16; ++j) {
      float acc = b_ih[j] + b_hh[j];
#pragma unroll
      for (int q = 0; q < 4; ++q) {
        acc = fmaf(xv[q], w_ih[j * 4 + q], acc);
        acc = fmaf(h[q], w_hh[j * 4 + q], acc);
      }
      gates[j] = acc;
    }
#pragma unroll
    for (int q = 0; q < 4; ++q) {
      float ig = sigmoidf_(gates[q]);
      float fg = sigmoidf_(gates[4 + q]);
      float gg = tanhf(gates[8 + q]);
      float og = sigmoidf_(gates[12 + q]);
      float cc = fmaf(fg, c[q], ig * gg);
      c[q] = cc;
      h[q] = og * tanhf(cc);
    }
  }
  float o0 = fc_b[0], o1 = fc_b[1];
#pragma unroll
  for (int q = 0; q < 4; ++q) {
    o0 = fmaf(h[q], fc_w[q], o0);
    o1 = fmaf(h[q], fc_w[4 + q], o1);
  }
  out[(size_t)g * 2]     = o0;
  out[(size_t)g * 2 + 1] = o1;
}

// ---------------------------------------------------------------------------
extern "C" void kernel_launch(void* const* d_in, const int* in_sizes, int n_in,
                              void* d_out, int out_size, void* d_ws, size_t ws_size,
                              hipStream_t stream) {
  const float* x     = (const float*)d_in[0];
  const int*   ei    = (const int*)d_in[1];
  const float* ew    = (const float*)d_in[3];
  const float* lin_w = (const float*)d_in[4];
  const float* lin_b = (const float*)d_in[5];
  const float* w_ih  = (const float*)d_in[6];
  const float* b_ih  = (const float*)d_in[7];
  const float* w_hh  = (const float*)d_in[8];
  const float* b_hh  = (const float*)d_in[9];
  const float* fc_w  = (const float*)d_in[10];
  const float* fc_b  = (const float*)d_in[11];
  float* out = (float*)d_out;

  const long long E_total = (long long)in_sizes[1] / 2;

  // workspace: P powers [8][3][16][64][4] f32 (384 KB), then pooled [1024][8][4]
  float* Pws    = (float*)d_ws;
  float* pooled = Pws + NS * 12288;

  hipLaunchKernelGGL(build_powers_kernel, dim3(NS), dim3(256), 0, stream,
                     ei, E_total, ew, Pws);
  hipLaunchKernelGGL(tag_pool_kernel, dim3(1024), dim3(256), 0, stream,
                     x, Pws, lin_w, lin_b, pooled);
  hipLaunchKernelGGL(lstm_fc_kernel, dim3(NB / 64), dim3(64), 0, stream,
                     pooled, w_ih, b_ih, w_hh, b_hh, fc_w, fc_b, out);
}

// Round 10
// 59.734 us; speedup vs baseline: 1.3595x; 1.3595x over previous
//
#include <hip/hip_runtime.h>
#include <math.h>

#define NC    64
#define NT    128
#define NS    8
#define NFEAT 16
#define NE1   4032
#define NB    1024

typedef __attribute__((ext_vector_type(8))) short short8v;   // 8 bf16 carrier
typedef __attribute__((ext_vector_type(4))) float float4v;

__device__ __forceinline__ float sigmoidf_(float x) { return 1.f / (1.f + expf(-x)); }

__device__ __forceinline__ unsigned short bf16hi(float v) {
  return (unsigned short)(__float_as_uint(v) >> 16);
}
__device__ __forceinline__ float bf16hi_f(float v) {
  return __uint_as_float(__float_as_uint(v) & 0xffff0000u);
}

// ---------------------------------------------------------------------------
// Kernel A: block = (s, nt): build M_s (64x64, redundant per block, cheap),
// compute rows [nt*16, nt*16+16) of P2 = M^2 and P3 = M^3 (row chains are
// row-independent), then pack A-operand MFMA fragments (hi/lo bf16 split)
// for those rows in mfma_f32_16x16x32_bf16 A-layout: lane l holds
// A[row = nt*16 + (l&15)][k = 32*t6 + 8*(l>>4) + e], e=0..7,
// k-concat = [M | P2 | P3] (192 total).
// Afrag uint layout: [s][t6(6)][nt(4)][half(2)][lane(64)][4 uints]
//   => per-s stride = 6*4*2*256 = 12288 uints.
// ---------------------------------------------------------------------------
__global__ __launch_bounds__(256) void build_frags_kernel(
    const int* __restrict__ ei, long long E_total,
    const float* __restrict__ ew, unsigned int* __restrict__ Afrag) {
  const int s  = blockIdx.x & 7;
  const int nt = blockIdx.x >> 3;
  const int t  = threadIdx.x;
  const int lane = t & 63;

  __shared__ float M[64][64];       // M[c][r]
  __shared__ float P23[2][16][64];  // local rows of P2, P3
  __shared__ float deg[64];

  for (int i = t; i < 4096; i += 256) (&M[0][0])[i] = 0.f;
  if (t < 64) deg[t] = 0.f;
  __syncthreads();

  const int* row = ei;
  const int* col = ei + E_total;
  const float* w = ew + s * NE1;
  for (int e = t; e < NE1; e += 256) atomicAdd(&deg[col[e]], w[e]);
  __syncthreads();
  if (t < 64) { float d = deg[t]; deg[t] = (d > 0.f) ? rsqrtf(d) : 0.f; }
  __syncthreads();
  for (int e = t; e < NE1; e += 256) {
    int r = row[e], c = col[e];
    atomicAdd(&M[c][r], deg[r] * w[e] * deg[c]);
  }
  __syncthreads();

  // row chains: wave (t>>6) handles rows nt*16 + (t>>6)*4 + (lane>>4);
  // lanes cover j-chunk (lane&15)*4 with float4 math.
  {
    const int rowl = ((t >> 6) << 2) | (lane >> 4);   // 0..15
    const int i    = (nt << 4) | rowl;
    const int jg4  = (lane & 15) << 2;
    float4v a2 = {0.f, 0.f, 0.f, 0.f};
#pragma unroll 8
    for (int m = 0; m < 64; ++m) {
      const float pim = M[i][m];
      const float4v mj = *(const float4v*)(&M[m][jg4]);
      a2 += pim * mj;
    }
    *(float4v*)(&P23[0][rowl][jg4]) = a2;
    float4v a3 = {0.f, 0.f, 0.f, 0.f};
#pragma unroll 8
    for (int m = 0; m < 64; ++m) {
      const float v2m = P23[0][rowl][m];              // same-wave DS ordering
      const float4v mj = *(const float4v*)(&M[m][jg4]);
      a3 += v2m * mj;
    }
    *(float4v*)(&P23[1][rowl][jg4]) = a3;
  }
  __syncthreads();   // packing reads all 16 rows across waves

  // pack 768 slots (t6, half, lane-frag), 3 per thread
  for (int slot = t; slot < 768; slot += 256) {
    const int t6 = slot >> 7;
    const int h  = (slot >> 6) & 1;
    const int lf = slot & 63;
    const int rl = lf & 15;                 // local row
    const int kb = (t6 << 5) | ((lf >> 4) << 3);
    uint4 u;
    unsigned int uu[4];
#pragma unroll
    for (int j = 0; j < 4; ++j) {
      unsigned short us[2];
#pragma unroll
      for (int e2 = 0; e2 < 2; ++e2) {
        const int k  = kb + (j << 1) + e2;
        const int kk = k >> 6;
        const int m  = k & 63;
        const float v = (kk == 0) ? M[(nt << 4) | rl][m] : P23[kk - 1][rl][m];
        us[e2] = h ? bf16hi(v - bf16hi_f(v)) : bf16hi(v);
      }
      uu[j] = (unsigned int)us[0] | ((unsigned int)us[1] << 16);
    }
    u.x = uu[0]; u.y = uu[1]; u.z = uu[2]; u.w = uu[3];
    unsigned int* dst = Afrag + ((((size_t)(s * 6 + t6) * 4 + nt) * 2 + h) << 8) + (lf << 2);
    *(uint4*)dst = u;
  }
}

// ---------------------------------------------------------------------------
// Kernel B: fused TAGConv (MFMA powers form) + ReLU + max-pool.
// out[64,4] = V0 + [M|P2|P3](64x192) @ [V1;V2;V3](192x4) per (graph,step).
// Wave handles 2 graphs of step s. A-fragments stream from global/L2
// (coalesced 16B/lane). B-fragments (z = V1..V3 hi/lo bf16) come from
// per-wave private LDS rows (o-stride 160B, 16B-aligned for ds_read_b128).
// acc += Ahi*Bhi + Alo*Bhi + Ahi*Blo (Alo*Blo ~2^-16, dropped).
// No __syncthreads (wave-private LDS only).
// ---------------------------------------------------------------------------
__global__ __launch_bounds__(256) void tag_pool_mfma_kernel(
    const float* __restrict__ x, const unsigned int* __restrict__ Afrag,
    const float* __restrict__ lin_w, const float* __restrict__ lin_b,
    float* __restrict__ pooled) {
  const int t    = threadIdx.x;
  const int lane = t & 63;
  const int w    = t >> 6;
  const int s    = blockIdx.x & 7;
  const int g0   = (((blockIdx.x >> 3) << 2) | w) << 1;   // 2 graphs/wave

  __shared__ unsigned short zT[4][2][2][3][4][80];  // [wave][g][hi/lo][kk][o][m pad80]
  __shared__ float V0T[4][2][4][72];                // [wave][g][o][n pad72]

  // early x loads (both graphs)
  float xf0[16], xf1[16];
  {
    const float* xr0 = x + (((size_t)(g0 + 0) << 6) + lane) * NT + s * NFEAT;
    const float* xr1 = x + (((size_t)(g0 + 1) << 6) + lane) * NT + s * NFEAT;
#pragma unroll
    for (int i = 0; i < 4; ++i) {
      *(float4*)(&xf0[i << 2]) = *(const float4*)(xr0 + (i << 2));
      *(float4*)(&xf1[i << 2]) = *(const float4*)(xr1 + (i << 2));
    }
  }

  // stage 1: V[k][o] = sum_f x[f]*W[k*4+o][f]; W via uniform (scalar) loads
#pragma unroll
  for (int k = 0; k < 4; ++k) {
#pragma unroll
    for (int o = 0; o < 4; ++o) {
      const float* wr = lin_w + ((k << 2) | o) * 16;
      float a0 = 0.f, a1 = 0.f;
#pragma unroll
      for (int f = 0; f < 16; ++f) {
        const float wv = wr[f];
        a0 = fmaf(xf0[f], wv, a0);
        a1 = fmaf(xf1[f], wv, a1);
      }
      if (k == 0) {
        V0T[w][0][o][lane] = a0;
        V0T[w][1][o][lane] = a1;
      } else {
        zT[w][0][0][k - 1][o][lane] = bf16hi(a0);
        zT[w][0][1][k - 1][o][lane] = bf16hi(a0 - bf16hi_f(a0));
        zT[w][1][0][k - 1][o][lane] = bf16hi(a1);
        zT[w][1][1][k - 1][o][lane] = bf16hi(a1 - bf16hi_f(a1));
      }
    }
  }

  // main loop over 6 k-steps of 32
  float4v acc[2][4];
#pragma unroll
  for (int g = 0; g < 2; ++g)
#pragma unroll
    for (int nt = 0; nt < 4; ++nt) acc[g][nt] = (float4v){0.f, 0.f, 0.f, 0.f};

  const unsigned int* Ab = Afrag + (size_t)s * 12288 + (lane << 2);
#pragma unroll 2
  for (int t6 = 0; t6 < 6; ++t6) {
    short8v Ah[4], Al[4];
#pragma unroll
    for (int nt = 0; nt < 4; ++nt) {
      Ah[nt] = *(const short8v*)(Ab + ((((t6 << 2) | nt) << 1) << 8));
      Al[nt] = *(const short8v*)(Ab + (((((t6 << 2) | nt) << 1) | 1) << 8));
    }
    const int kk   = t6 >> 1;
    const int mloc = ((t6 & 1) << 5) | ((lane >> 4) << 3);
    const int oc   = lane & 3;   // valid for output cols 0..3 (lanes l&15<4)
    const short8v Bh0 = *(const short8v*)(&zT[w][0][0][kk][oc][mloc]);
    const short8v Bl0 = *(const short8v*)(&zT[w][0][1][kk][oc][mloc]);
    const short8v Bh1 = *(const short8v*)(&zT[w][1][0][kk][oc][mloc]);
    const short8v Bl1 = *(const short8v*)(&zT[w][1][1][kk][oc][mloc]);
#pragma unroll
    for (int nt = 0; nt < 4; ++nt) {
      acc[0][nt] = __builtin_amdgcn_mfma_f32_16x16x32_bf16(Ah[nt], Bh0, acc[0][nt], 0, 0, 0);
      acc[0][nt] = __builtin_amdgcn_mfma_f32_16x16x32_bf16(Al[nt], Bh0, acc[0][nt], 0, 0, 0);
      acc[0][nt] = __builtin_amdgcn_mfma_f32_16x16x32_bf16(Ah[nt], Bl0, acc[0][nt], 0, 0, 0);
      acc[1][nt] = __builtin_amdgcn_mfma_f32_16x16x32_bf16(Ah[nt], Bh1, acc[1][nt], 0, 0, 0);
      acc[1][nt] = __builtin_amdgcn_mfma_f32_16x16x32_bf16(Al[nt], Bh1, acc[1][nt], 0, 0, 0);
      acc[1][nt] = __builtin_amdgcn_mfma_f32_16x16x32_bf16(Ah[nt], Bl1, acc[1][nt], 0, 0, 0);
    }
  }

  // epilogue: + V0 + bias, relu, max over 64 rows (per col), store cols 0..3
  const float bsA = lin_b[0] + lin_b[4] + lin_b[8]  + lin_b[12];
  const float bsB = lin_b[1] + lin_b[5] + lin_b[9]  + lin_b[13];
  const float bsC = lin_b[2] + lin_b[6] + lin_b[10] + lin_b[14];
  const float bsD = lin_b[3] + lin_b[7] + lin_b[11] + lin_b[15];
  const int oc = lane & 3;
  const float bs = (oc == 0) ? bsA : (oc == 1) ? bsB : (oc == 2) ? bsC : bsD;

#pragma unroll
  for (int g = 0; g < 2; ++g) {
    float mx = 0.f;   // relu floor: outputs are >= 0
#pragma unroll
    for (int nt = 0; nt < 4; ++nt) {
      const float4v v0 = *(const float4v*)(&V0T[w][g][oc][(nt << 4) | ((lane >> 4) << 2)]);
#pragma unroll
      for (int r = 0; r < 4; ++r) {
        float ov = acc[g][nt][r] + v0[r] + bs;
        ov = fmaxf(ov, 0.f);
        mx = fmaxf(mx, ov);
      }
    }
    mx = fmaxf(mx, __shfl_xor(mx, 16));
    mx = fmaxf(mx, __shfl_xor(mx, 32));
    if (lane < 4)
      pooled[((size_t)(g0 + g) * NS + s) * 4 + lane] = mx;
  }
}

// ---------------------------------------------------------------------------
// Kernel C: LSTM (hidden 4, 8 steps) + FC. One thread per graph.
// ---------------------------------------------------------------------------
__global__ __launch_bounds__(64) void lstm_fc_kernel(
    const float* __restrict__ pooled,
    const float* __restrict__ w_ih, const float* __restrict__ b_ih,
    const float* __restrict__ w_hh, const float* __restrict__ b_hh,
    const float* __restrict__ fc_w, const float* __restrict__ fc_b,
    float* __restrict__ out) {
  const int g = blockIdx.x * blockDim.x + threadIdx.x;
  if (g >= NB) return;
  float h[4] = {0.f, 0.f, 0.f, 0.f};
  float c[4] = {0.f, 0.f, 0.f, 0.f};
  for (int s = 0; s < NS; ++s) {
    float4 xt4 = *(const float4*)(pooled + (((size_t)g << 3) + s) * 4);
    const float xv[4] = {xt4.x, xt4.y, xt4.z, xt4.w};
    float gates[16];
#pragma unroll
    for (int j = 0; j < 16; ++j) {
      float acc = b_ih[j] + b_hh[j];
#pragma unroll
      for (int q = 0; q < 4; ++q) {
        acc = fmaf(xv[q], w_ih[j * 4 + q], acc);
        acc = fmaf(h[q], w_hh[j * 4 + q], acc);
      }
      gates[j] = acc;
    }
#pragma unroll
    for (int q = 0; q < 4; ++q) {
      float ig = sigmoidf_(gates[q]);
      float fg = sigmoidf_(gates[4 + q]);
      float gg = tanhf(gates[8 + q]);
      float og = sigmoidf_(gates[12 + q]);
      float cc = fmaf(fg, c[q], ig * gg);
      c[q] = cc;
      h[q] = og * tanhf(cc);
    }
  }
  float o0 = fc_b[0], o1 = fc_b[1];
#pragma unroll
  for (int q = 0; q < 4; ++q) {
    o0 = fmaf(h[q], fc_w[q], o0);
    o1 = fmaf(h[q], fc_w[4 + q], o1);
  }
  out[(size_t)g * 2]     = o0;
  out[(size_t)g * 2 + 1] = o1;
}

// ---------------------------------------------------------------------------
extern "C" void kernel_launch(void* const* d_in, const int* in_sizes, int n_in,
                              void* d_out, int out_size, void* d_ws, size_t ws_size,
                              hipStream_t stream) {
  const float* x     = (const float*)d_in[0];
  const int*   ei    = (const int*)d_in[1];
  const float* ew    = (const float*)d_in[3];
  const float* lin_w = (const float*)d_in[4];
  const float* lin_b = (const float*)d_in[5];
  const float* w_ih  = (const float*)d_in[6];
  const float* b_ih  = (const float*)d_in[7];
  const float* w_hh  = (const float*)d_in[8];
  const float* b_hh  = (const float*)d_in[9];
  const float* fc_w  = (const float*)d_in[10];
  const float* fc_b  = (const float*)d_in[11];
  float* out = (float*)d_out;

  const long long E_total = (long long)in_sizes[1] / 2;

  // ws: Afrag [8][6][4][2][64][4] uint (384 KB), then pooled [1024][8][4] f32
  unsigned int* Afrag = (unsigned int*)d_ws;
  float* pooled = (float*)(Afrag + (size_t)NS * 12288);

  hipLaunchKernelGGL(build_frags_kernel, dim3(32), dim3(256), 0, stream,
                     ei, E_total, ew, Afrag);
  hipLaunchKernelGGL(tag_pool_mfma_kernel, dim3(1024), dim3(256), 0, stream,
                     x, Afrag, lin_w, lin_b, pooled);
  hipLaunchKernelGGL(lstm_fc_kernel, dim3(NB / 64), dim3(64), 0, stream,
                     pooled, w_ih, b_ih, w_hh, b_hh, fc_w, fc_b, out);
}